// Round 1
// 918.061 us; speedup vs baseline: 1.1192x; 1.1192x over previous
//
#include <hip/hip_runtime.h>

// MultiDense: y[b,n,o] = sum_i x[b,n,i]*A[0,n,o,i] + Bp[0,n,o]
// B_SZ=2048, NSPLIT=256, OUT=256, IN=256. fp32 in/out; bf16 MFMA compute.
//
// Structure: 1 block per group n (256 blocks = 1/CU, forced by 129KB LDS).
// A_n staged ONCE to LDS as bf16 in MFMA B-fragment order (lane-linear
// ds_read_b128 -> conflict-free). 16 waves each own 128 rows of x, stream
// X global->register with depth-2 prefetch. No barriers in the main loop.

#define NS     256
#define OUTD   256
#define IND    256
#define ROWF   65536          // floats between consecutive batch rows (NS*IND)

typedef __bf16 bf16x8 __attribute__((ext_vector_type(8)));
typedef float  floatx4 __attribute__((ext_vector_type(4)));

__global__ __launch_bounds__(1024, 4)
void md_kernel(const float* __restrict__ x,
               const float* __restrict__ A,
               const float* __restrict__ Bp,
               float* __restrict__ out) {
    extern __shared__ char smem[];
    __bf16* As     = (__bf16*)smem;            // 128 KB: entry e = (ks*16 + ofrag)*64 + lane, 8 bf16 each
    float*  bias_s = (float*)(smem + 131072);  // 1 KB

    const int n    = blockIdx.x;
    const int t    = threadIdx.x;
    const int w    = t >> 6;        // wave 0..15
    const int lane = t & 63;
    const int l15  = lane & 15;
    const int lq   = lane >> 4;

    // ---- stage A_n (fp32) -> LDS bf16, pre-arranged in B-fragment order ----
    // entry e holds A[ofrag*16 + (e&15)][ks*32 + ((e>>4)&3)*8 .. +8)
    {
        const float* Ag = A + (size_t)n * (OUTD * IND);
#pragma unroll
        for (int it = 0; it < 8; ++it) {
            const int e  = it * 1024 + t;
            const int o  = (((e >> 6) & 15) << 4) | (e & 15);
            const int k0 = ((e >> 10) << 5) | (((e >> 4) & 3) << 3);
            const float* src = Ag + o * IND + k0;
            const floatx4 p0 = *(const floatx4*)src;
            const floatx4 p1 = *(const floatx4*)(src + 4);
            bf16x8 v;
            v[0]=(__bf16)p0[0]; v[1]=(__bf16)p0[1]; v[2]=(__bf16)p0[2]; v[3]=(__bf16)p0[3];
            v[4]=(__bf16)p1[0]; v[5]=(__bf16)p1[1]; v[6]=(__bf16)p1[2]; v[7]=(__bf16)p1[3];
            *(bf16x8*)(As + (size_t)e * 8) = v;   // lane-linear 16B writes: conflict-free
        }
        if (t < OUTD) bias_s[t] = Bp[n * OUTD + t];
    }
    __syncthreads();   // the only barrier in the kernel

    // ---- wave w: rows [w*128, w*128+128), all 256 outputs, K streamed ----
    const float* xw = x + (size_t)(w * 128 + l15) * ROWF + n * IND + lq * 8;
    float*       ow = out + (size_t)(w * 128) * ROWF + n * OUTD;

    floatx4 acc[16];
#pragma unroll
    for (int j = 0; j < 16; ++j) acc[j] = (floatx4){0.f, 0.f, 0.f, 0.f};

    // round q (0..63): tile = q>>3 (16 rows), ks = q&7 (K-step of 32)
#define XADDR(q) (xw + (size_t)((q) >> 3) * (16 * ROWF) + ((q) & 7) * 32)

    // depth-2 prefetch, two explicit slots (static indexing -> no scratch)
    floatx4 s0a = *(const floatx4*)XADDR(0);
    floatx4 s0b = *(const floatx4*)(XADDR(0) + 4);
    floatx4 s1a = *(const floatx4*)XADDR(1);
    floatx4 s1b = *(const floatx4*)(XADDR(1) + 4);

#define BODY(q, sa, sb)                                                          \
    {                                                                            \
        bf16x8 a;                                                                \
        a[0]=(__bf16)sa[0]; a[1]=(__bf16)sa[1]; a[2]=(__bf16)sa[2]; a[3]=(__bf16)sa[3]; \
        a[4]=(__bf16)sb[0]; a[5]=(__bf16)sb[1]; a[6]=(__bf16)sb[2]; a[7]=(__bf16)sb[3]; \
        if ((q) < 62) {                                                          \
            sa = *(const floatx4*)XADDR((q) + 2);                                \
            sb = *(const floatx4*)(XADDR((q) + 2) + 4);                          \
        }                                                                        \
        const __bf16* bp = As + ((q) & 7) * 8192 + lane * 8;                     \
        _Pragma("unroll")                                                        \
        for (int j = 0; j < 16; ++j) {                                           \
            const bf16x8 b = *(const bf16x8*)(bp + j * 512);                     \
            acc[j] = __builtin_amdgcn_mfma_f32_16x16x32_bf16(a, b, acc[j], 0, 0, 0); \
        }                                                                        \
        if (((q) & 7) == 7) {  /* tile done: epilogue */                         \
            float* og = ow + (size_t)((q) >> 3) * (16 * ROWF);                   \
            _Pragma("unroll")                                                    \
            for (int j = 0; j < 16; ++j) {                                       \
                const float bb = bias_s[j * 16 + l15];                           \
                _Pragma("unroll")                                                \
                for (int r = 0; r < 4; ++r)                                      \
                    og[(size_t)(lq * 4 + r) * ROWF + j * 16 + l15] = acc[j][r] + bb; \
                acc[j] = (floatx4){0.f, 0.f, 0.f, 0.f};                          \
            }                                                                    \
        }                                                                        \
    }

#pragma unroll 1
    for (int qq = 0; qq < 32; ++qq) {
        const int q0 = qq * 2;
        BODY(q0,     s0a, s0b);
        BODY(q0 + 1, s1a, s1b);
    }
#undef BODY
#undef XADDR
}

extern "C" void kernel_launch(void* const* d_in, const int* in_sizes, int n_in,
                              void* d_out, int out_size, void* d_ws, size_t ws_size,
                              hipStream_t stream) {
    const float* x  = (const float*)d_in[0];
    const float* A  = (const float*)d_in[1];
    const float* Bp = (const float*)d_in[2];
    float* out = (float*)d_out;

    static bool attr_done = false;
    if (!attr_done) {
        hipFuncSetAttribute((const void*)md_kernel,
                            hipFuncAttributeMaxDynamicSharedMemorySize, 132096);
        attr_done = true;
    }

    hipLaunchKernelGGL(md_kernel, dim3(NS), dim3(1024), 132096, stream,
                       x, A, Bp, out);
}

// Round 2
// 915.096 us; speedup vs baseline: 1.1228x; 1.0032x over previous
//
#include <hip/hip_runtime.h>

// MultiDense: y[b,n,o] = sum_i x[b,n,i]*A[0,n,o,i] + Bp[0,n,o]
// B_SZ=2048, NSPLIT=256, OUT=256, IN=256. fp32 in/out; bf16 MFMA compute.
//
// Structure: 1 block per group n (256 blocks = 1/CU, forced by 129KB LDS).
// A_n staged ONCE to LDS as bf16 in MFMA fragment order (lane-linear
// ds_read_b128 -> conflict-free). 16 waves each own 128 rows of x, stream
// X global->register with depth-2 prefetch. No barriers in the main loop.
// MFMA operands: a = A-matrix frag (M dim = o), b = x frag (N dim = m).
// => D frag: col(lane&15) = m, row(lq*4+r) = o  ==> float4 epilogue stores.

#define NS     256
#define OUTD   256
#define IND    256
#define ROWF   65536          // floats between consecutive batch rows (NS*IND)

typedef __bf16 bf16x8 __attribute__((ext_vector_type(8)));
typedef float  floatx4 __attribute__((ext_vector_type(4)));

__global__ __launch_bounds__(1024, 4)
void md_kernel(const float* __restrict__ x,
               const float* __restrict__ A,
               const float* __restrict__ Bp,
               float* __restrict__ out) {
    extern __shared__ char smem[];
    __bf16* As     = (__bf16*)smem;            // 128 KB: entry e = (ks*16 + ofrag)*64 + lane, 8 bf16 each
    float*  bias_s = (float*)(smem + 131072);  // 1 KB

    const int n    = blockIdx.x;
    const int t    = threadIdx.x;
    const int w    = t >> 6;        // wave 0..15
    const int lane = t & 63;
    const int l15  = lane & 15;
    const int lq   = lane >> 4;

    // ---- wave w: rows [w*128, w*128+128), all 256 outputs, K streamed ----
    const float* xw = x + (size_t)(w * 128 + l15) * ROWF + n * IND + lq * 8;
    float*       ow = out + (size_t)(w * 128 + l15) * ROWF + n * OUTD;

    // round q (0..63): tile = q>>3 (16 rows), ks = q&7 (K-step of 32)
#define XADDR(q) (xw + (size_t)((q) >> 3) * (16 * ROWF) + ((q) & 7) * 32)

    // Issue the first two prefetch slots BEFORE A staging: their HBM
    // latency + queue delay overlaps the staging phase.
    floatx4 s0a = *(const floatx4*)XADDR(0);
    floatx4 s0b = *(const floatx4*)(XADDR(0) + 4);
    floatx4 s1a = *(const floatx4*)XADDR(1);
    floatx4 s1b = *(const floatx4*)(XADDR(1) + 4);

    // ---- stage A_n (fp32) -> LDS bf16, pre-arranged in fragment order ----
    // entry e holds A[ofrag*16 + (e&15)][ks*32 + ((e>>4)&3)*8 .. +8)
    {
        const float* Ag = A + (size_t)n * (OUTD * IND);
#pragma unroll
        for (int it = 0; it < 8; ++it) {
            const int e  = it * 1024 + t;
            const int o  = (((e >> 6) & 15) << 4) | (e & 15);
            const int k0 = ((e >> 10) << 5) | (((e >> 4) & 3) << 3);
            const float* src = Ag + o * IND + k0;
            const floatx4 p0 = *(const floatx4*)src;
            const floatx4 p1 = *(const floatx4*)(src + 4);
            bf16x8 v;
            v[0]=(__bf16)p0[0]; v[1]=(__bf16)p0[1]; v[2]=(__bf16)p0[2]; v[3]=(__bf16)p0[3];
            v[4]=(__bf16)p1[0]; v[5]=(__bf16)p1[1]; v[6]=(__bf16)p1[2]; v[7]=(__bf16)p1[3];
            *(bf16x8*)(As + (size_t)e * 8) = v;   // lane-linear 16B writes: conflict-free
        }
        if (t < OUTD) bias_s[t] = Bp[n * OUTD + t];
    }
    __syncthreads();   // the only barrier in the kernel

    floatx4 acc[16];
#pragma unroll
    for (int j = 0; j < 16; ++j) acc[j] = (floatx4){0.f, 0.f, 0.f, 0.f};

#define BODY(q, sa, sb)                                                          \
    {                                                                            \
        bf16x8 xb;                                                               \
        xb[0]=(__bf16)sa[0]; xb[1]=(__bf16)sa[1]; xb[2]=(__bf16)sa[2]; xb[3]=(__bf16)sa[3]; \
        xb[4]=(__bf16)sb[0]; xb[5]=(__bf16)sb[1]; xb[6]=(__bf16)sb[2]; xb[7]=(__bf16)sb[3]; \
        if ((q) < 62) {                                                          \
            sa = *(const floatx4*)XADDR((q) + 2);                                \
            sb = *(const floatx4*)(XADDR((q) + 2) + 4);                          \
        }                                                                        \
        const __bf16* ap = As + ((q) & 7) * 8192 + lane * 8;                     \
        _Pragma("unroll")                                                        \
        for (int j = 0; j < 16; ++j) {                                           \
            const bf16x8 af = *(const bf16x8*)(ap + j * 512);                    \
            acc[j] = __builtin_amdgcn_mfma_f32_16x16x32_bf16(af, xb, acc[j], 0, 0, 0); \
        }                                                                        \
        if (((q) & 7) == 7) {  /* tile done: epilogue */                         \
            float* og = ow + (size_t)((q) >> 3) * (16 * ROWF);                   \
            _Pragma("unroll")                                                    \
            for (int j = 0; j < 16; ++j) {                                       \
                const floatx4 bb = *(const floatx4*)(&bias_s[j * 16 + lq * 4]);  \
                floatx4 v = acc[j];                                              \
                v[0] += bb[0]; v[1] += bb[1]; v[2] += bb[2]; v[3] += bb[3];      \
                *(floatx4*)(og + j * 16 + lq * 4) = v;                           \
                acc[j] = (floatx4){0.f, 0.f, 0.f, 0.f};                          \
            }                                                                    \
        }                                                                        \
    }

#pragma unroll 1
    for (int qq = 0; qq < 32; ++qq) {
        const int q0 = qq * 2;
        BODY(q0,     s0a, s0b);
        BODY(q0 + 1, s1a, s1b);
    }
#undef BODY
#undef XADDR
}

extern "C" void kernel_launch(void* const* d_in, const int* in_sizes, int n_in,
                              void* d_out, int out_size, void* d_ws, size_t ws_size,
                              hipStream_t stream) {
    const float* x  = (const float*)d_in[0];
    const float* A  = (const float*)d_in[1];
    const float* Bp = (const float*)d_in[2];
    float* out = (float*)d_out;

    static bool attr_done = false;
    if (!attr_done) {
        hipFuncSetAttribute((const void*)md_kernel,
                            hipFuncAttributeMaxDynamicSharedMemorySize, 132096);
        attr_done = true;
    }

    hipLaunchKernelGGL(md_kernel, dim3(NS), dim3(1024), 132096, stream,
                       x, A, Bp, out);
}